// Round 4
// baseline (283.268 us; speedup 1.0000x reference)
//
#include <hip/hip_runtime.h>

// VQ-VAE quantizer. x:[32][64][64][64] f32 NCHW, codebook:[512][64] f32.
// d_out = quantized[8388608] ++ loss[1] ++ hist[32*512], all f32.
//
// CORRECTNESS-CRITICAL: the reference computes dist = S1 + S2 - 2*(x@e.T)
// entirely in fp32. Adding the ~64-magnitude S1 quantizes distances to a
// ~7.6e-6 grid; ~170 points have their top-2 distances snap EQUAL, and
// argmin then picks the LOWER INDEX. We must reproduce that exact fp32
// rounding (exact fp64 argmin fails: rounds 0/1 both absmax=2 on hist).
//  - dot: sequential fp32 FMA chain over c ascending (= BLAS/XLA rank-1
//    update accumulation order), via __fmaf_rn.
//  - S1/S2: numpy pairwise_sum for n=64 (8 accumulators, pairwise combine),
//    every square/add individually rounded (__fmul_rn/__fadd_rn also stop
//    -ffp-contract=fast from fusing them).
//  - D = fp32(fp32(S1+S2_k) - 2a): 2a is exact, so fmaf(-2,a,t1) == the
//    reference's two-step rounding.
#define CDIM 64
#define KCB  512
#define HW   4096          // H*W
#define NPTS (32 * HW)     // 131072
#define OUTQ (32 * CDIM * HW)  // 8388608

__global__ __launch_bounds__(256) void vq_zero_tail(float* __restrict__ tail, int n) {
    int i = blockIdx.x * 256 + threadIdx.x;
    if (i < n) tail[i] = 0.0f;
}

// numpy pairwise_sum of v[c]^2, n=64 (8-acc unrolled block, pairwise combine)
__device__ __forceinline__ float np_sumsq64(const float* __restrict__ v) {
    float r0 = __fmul_rn(v[0], v[0]), r1 = __fmul_rn(v[1], v[1]);
    float r2 = __fmul_rn(v[2], v[2]), r3 = __fmul_rn(v[3], v[3]);
    float r4 = __fmul_rn(v[4], v[4]), r5 = __fmul_rn(v[5], v[5]);
    float r6 = __fmul_rn(v[6], v[6]), r7 = __fmul_rn(v[7], v[7]);
#pragma unroll
    for (int i = 8; i < 64; i += 8) {
        r0 = __fadd_rn(r0, __fmul_rn(v[i + 0], v[i + 0]));
        r1 = __fadd_rn(r1, __fmul_rn(v[i + 1], v[i + 1]));
        r2 = __fadd_rn(r2, __fmul_rn(v[i + 2], v[i + 2]));
        r3 = __fadd_rn(r3, __fmul_rn(v[i + 3], v[i + 3]));
        r4 = __fadd_rn(r4, __fmul_rn(v[i + 4], v[i + 4]));
        r5 = __fadd_rn(r5, __fmul_rn(v[i + 5], v[i + 5]));
        r6 = __fadd_rn(r6, __fmul_rn(v[i + 6], v[i + 6]));
        r7 = __fadd_rn(r7, __fmul_rn(v[i + 7], v[i + 7]));
    }
    return __fadd_rn(__fadd_rn(__fadd_rn(r0, r1), __fadd_rn(r2, r3)),
                     __fadd_rn(__fadd_rn(r4, r5), __fadd_rn(r6, r7)));
}

__global__ __launch_bounds__(256) void vq_main(const float* __restrict__ x,
                                               const float* __restrict__ cb,
                                               float* __restrict__ out) {
    __shared__ float    s2[KCB];
    __shared__ unsigned hist[KCB];
    const int tid = threadIdx.x;

    // --- per-block: S2[k] = np.sum(e_k**2) (numpy pairwise) + hist zero ---
    for (int k = tid; k < KCB; k += 256) {
        s2[k] = np_sumsq64(cb + k * CDIM);
        hist[k] = 0u;
    }
    __syncthreads();

    // --- load this thread's point (coalesced across lanes for each c) ---
    const int n = blockIdx.x * 256 + tid;   // grid sized exactly NPTS/256
    const int b = n >> 12;                  // image index (4096 px / image)
    const int p = n & 4095;                 // pixel within image
    const float* xb = x + b * (CDIM * HW) + p;
    float xr[CDIM];
#pragma unroll
    for (int c = 0; c < CDIM; ++c) xr[c] = xb[c * HW];

    // --- S1 = np.sum(x**2) in numpy's exact fp32 order ---
    const float S1 = np_sumsq64(xr);

    // --- argmin over D_k = fp32(fp32(S1+S2_k) - 2*dot), reference rounding ---
    float best = 3.4e38f;
    int   bidx = 0;
    for (int k = 0; k < KCB; k += 4) {
#pragma unroll
        for (int kk = 0; kk < 4; ++kk) {
            const float* e = cb + (k + kk) * CDIM;   // wave-uniform -> s_load
            float a = 0.f;
#pragma unroll
            for (int c = 0; c < CDIM; ++c) a = __fmaf_rn(xr[c], e[c], a);
            float t1 = __fadd_rn(S1, s2[k + kk]);
            float D  = __fmaf_rn(-2.0f, a, t1);      // == fp32(t1 - fp32(2a))
            bool lt = (D < best);                    // strict <: first-min tie break
            bidx = lt ? (k + kk) : bidx;
            best = lt ? D : best;
        }
    }

    atomicAdd(&hist[bidx], 1u);

    // --- epilogue: straight-through write + squared-diff accumulation ---
    const float* e = cb + bidx * CDIM;      // per-lane gather (L2-resident, 128KB)
    float* ob = out + b * (CDIM * HW) + p;
    float ds = 0.f;
#pragma unroll
    for (int c = 0; c < CDIM; ++c) {
        float q = e[c];
        float d = q - xr[c];
        ds = fmaf(d, d, ds);
        ob[c * HW] = xr[c] + d;             // emulate x + (q - x) rounding
    }

    // --- loss: wave shuffle reduce -> block reduce -> one atomic ---
#pragma unroll
    for (int off = 32; off > 0; off >>= 1) ds += __shfl_down(ds, off, 64);
    __shared__ float wsum[4];
    if ((tid & 63) == 0) wsum[tid >> 6] = ds;
    __syncthreads();                        // also orders LDS hist atomics
    if (tid == 0) {
        float s = (wsum[0] + wsum[1]) + (wsum[2] + wsum[3]);
        atomicAdd(out + OUTQ, s * (1.25f / (float)OUTQ));
    }

    // --- flush per-block histogram (block touches exactly one image) ---
    float* ho = out + OUTQ + 1 + b * KCB;
    for (int k = tid; k < KCB; k += 256) {
        unsigned cnt = hist[k];
        if (cnt) atomicAdd(ho + k, (float)cnt);
    }
}

extern "C" void kernel_launch(void* const* d_in, const int* in_sizes, int n_in,
                              void* d_out, int out_size, void* d_ws, size_t ws_size,
                              hipStream_t stream) {
    const float* x  = (const float*)d_in[0];
    const float* cb = (const float*)d_in[1];
    float* out = (float*)d_out;

    const int tail = 1 + 32 * KCB;  // loss + hist
    vq_zero_tail<<<(tail + 255) / 256, 256, 0, stream>>>(out + OUTQ, tail);
    vq_main<<<NPTS / 256, 256, 0, stream>>>(x, cb, out);
}

// Round 6
// 280.344 us; speedup vs baseline: 1.0104x; 1.0104x over previous
//
#include <hip/hip_runtime.h>

// VQ-VAE quantizer. x:[32][64][64][64] f32 NCHW, codebook:[512][64] f32.
// d_out = quantized[8388608] ++ loss[1] ++ hist[32*512], all f32.
//
// CORRECTNESS-CRITICAL (zero flip tolerance on hist): reproduce the
// reference's fp32 arithmetic exactly — see round-2 notes. Sequential
// __fmaf_rn chain over c (BLAS order), numpy pairwise S1/S2, two-step
// distance rounding, strict-< first-index argmin.
//
// PERF NOTE (round-4 post-mortem): without the 2nd launch_bounds arg the
// allocator capped arch VGPRs at 52 and spilled xr[64] to AGPRs —
// v_accvgpr_read per use doubled VALU traffic (VALUBusy 58%, only 24% of
// fp32 peak). Grid is 512 blocks = 2 blocks/CU = 2 waves/SIMD, so
// __launch_bounds__(256, 2) (VGPR cap 256) costs zero occupancy.
#define CDIM 64
#define KCB  512
#define HW   4096          // H*W
#define NPTS (32 * HW)     // 131072
#define OUTQ (32 * CDIM * HW)  // 8388608

__global__ __launch_bounds__(256) void vq_zero_tail(float* __restrict__ tail, int n) {
    int i = blockIdx.x * 256 + threadIdx.x;
    if (i < n) tail[i] = 0.0f;
}

// numpy pairwise_sum of v[c]^2, n=64 (8-acc unrolled block, pairwise combine)
__device__ __forceinline__ float np_sumsq64(const float* __restrict__ v) {
    float r0 = __fmul_rn(v[0], v[0]), r1 = __fmul_rn(v[1], v[1]);
    float r2 = __fmul_rn(v[2], v[2]), r3 = __fmul_rn(v[3], v[3]);
    float r4 = __fmul_rn(v[4], v[4]), r5 = __fmul_rn(v[5], v[5]);
    float r6 = __fmul_rn(v[6], v[6]), r7 = __fmul_rn(v[7], v[7]);
#pragma unroll
    for (int i = 8; i < 64; i += 8) {
        r0 = __fadd_rn(r0, __fmul_rn(v[i + 0], v[i + 0]));
        r1 = __fadd_rn(r1, __fmul_rn(v[i + 1], v[i + 1]));
        r2 = __fadd_rn(r2, __fmul_rn(v[i + 2], v[i + 2]));
        r3 = __fadd_rn(r3, __fmul_rn(v[i + 3], v[i + 3]));
        r4 = __fadd_rn(r4, __fmul_rn(v[i + 4], v[i + 4]));
        r5 = __fadd_rn(r5, __fmul_rn(v[i + 5], v[i + 5]));
        r6 = __fadd_rn(r6, __fmul_rn(v[i + 6], v[i + 6]));
        r7 = __fadd_rn(r7, __fmul_rn(v[i + 7], v[i + 7]));
    }
    return __fadd_rn(__fadd_rn(__fadd_rn(r0, r1), __fadd_rn(r2, r3)),
                     __fadd_rn(__fadd_rn(r4, r5), __fadd_rn(r6, r7)));
}

__global__ __launch_bounds__(256, 2) void vq_main(const float* __restrict__ x,
                                                  const float* __restrict__ cb,
                                                  float* __restrict__ out) {
    __shared__ float    s2[KCB];
    __shared__ unsigned hist[KCB];
    const int tid = threadIdx.x;

    // --- per-block: S2[k] = np.sum(e_k**2) (numpy pairwise) + hist zero ---
    for (int k = tid; k < KCB; k += 256) {
        s2[k] = np_sumsq64(cb + k * CDIM);
        hist[k] = 0u;
    }
    __syncthreads();

    // --- load this thread's point (coalesced across lanes for each c) ---
    const int n = blockIdx.x * 256 + tid;   // grid sized exactly NPTS/256
    const int b = n >> 12;                  // image index (4096 px / image)
    const int p = n & 4095;                 // pixel within image
    const float* xb = x + b * (CDIM * HW) + p;
    float xr[CDIM];
#pragma unroll
    for (int c = 0; c < CDIM; ++c) xr[c] = xb[c * HW];

    // --- S1 = np.sum(x**2) in numpy's exact fp32 order ---
    const float S1 = np_sumsq64(xr);

    // --- argmin over D_k = fp32(fp32(S1+S2_k) - 2*dot), reference rounding ---
    float best = 3.4e38f;
    int   bidx = 0;
    for (int k = 0; k < KCB; k += 4) {
#pragma unroll
        for (int kk = 0; kk < 4; ++kk) {
            const float* e = cb + (k + kk) * CDIM;   // wave-uniform -> s_load
            float a = 0.f;
#pragma unroll
            for (int c = 0; c < CDIM; ++c) a = __fmaf_rn(xr[c], e[c], a);
            float t1 = __fadd_rn(S1, s2[k + kk]);
            float D  = __fmaf_rn(-2.0f, a, t1);      // == fp32(t1 - fp32(2a))
            bool lt = (D < best);                    // strict <: first-min tie break
            bidx = lt ? (k + kk) : bidx;
            best = lt ? D : best;
        }
    }

    atomicAdd(&hist[bidx], 1u);

    // --- epilogue: straight-through write + squared-diff accumulation ---
    const float* e = cb + bidx * CDIM;      // per-lane gather (L2-resident, 128KB)
    float* ob = out + b * (CDIM * HW) + p;
    float ds = 0.f;
#pragma unroll
    for (int c = 0; c < CDIM; ++c) {
        float q = e[c];
        float d = q - xr[c];
        ds = fmaf(d, d, ds);
        ob[c * HW] = xr[c] + d;             // emulate x + (q - x) rounding
    }

    // --- loss: wave shuffle reduce -> block reduce -> one atomic ---
#pragma unroll
    for (int off = 32; off > 0; off >>= 1) ds += __shfl_down(ds, off, 64);
    __shared__ float wsum[4];
    if ((tid & 63) == 0) wsum[tid >> 6] = ds;
    __syncthreads();                        // also orders LDS hist atomics
    if (tid == 0) {
        float s = (wsum[0] + wsum[1]) + (wsum[2] + wsum[3]);
        atomicAdd(out + OUTQ, s * (1.25f / (float)OUTQ));
    }

    // --- flush per-block histogram (block touches exactly one image) ---
    float* ho = out + OUTQ + 1 + b * KCB;
    for (int k = tid; k < KCB; k += 256) {
        unsigned cnt = hist[k];
        if (cnt) atomicAdd(ho + k, (float)cnt);
    }
}

extern "C" void kernel_launch(void* const* d_in, const int* in_sizes, int n_in,
                              void* d_out, int out_size, void* d_ws, size_t ws_size,
                              hipStream_t stream) {
    const float* x  = (const float*)d_in[0];
    const float* cb = (const float*)d_in[1];
    float* out = (float*)d_out;

    const int tail = 1 + 32 * KCB;  // loss + hist
    vq_zero_tail<<<(tail + 255) / 256, 256, 0, stream>>>(out + OUTQ, tail);
    vq_main<<<NPTS / 256, 256, 0, stream>>>(x, cb, out);
}